// Round 1
// baseline (342.358 us; speedup 1.0000x reference)
//
#include <hip/hip_runtime.h>

#define A_N 8400
#define B_N 32
#define NGT 64
#define NC  80
#define BA  (B_N * A_N)

// Compute the task-aligned metric amf = (score^0.5 * iou^6) * in_gts for one
// (anchor, gt) pair, matching the numpy/JAX reference op-for-op.
// fp contract off so mul+add are not fused into fma (keeps us ~1ulp of numpy).
__device__ __forceinline__ float compute_amf(const float* __restrict__ pd_s,
                                             size_t row_off, int lab,
                                             float4 pb, float2 ap, float4 gb,
                                             bool& ing) {
#pragma clang fp contract(off)
  float lt0 = ap.x - gb.x;
  float lt1 = ap.y - gb.y;
  float rb0 = gb.z - ap.x;
  float rb1 = gb.w - ap.y;
  float mn = fminf(fminf(lt0, lt1), fminf(rb0, rb1));
  ing = mn > 0.0f;
  if (!ing) return 0.0f;   // align * False == +0.0 exactly
  float iw = fminf(gb.z, pb.z) - fmaxf(gb.x, pb.x);
  iw = fmaxf(iw, 0.0f);
  float ih = fminf(gb.w, pb.w) - fmaxf(gb.y, pb.y);
  ih = fmaxf(ih, 0.0f);
  float inter = iw * ih;
  float w1 = gb.z - gb.x, h1 = (gb.w - gb.y) + 1e-16f;
  float w2 = pb.z - pb.x, h2 = (pb.w - pb.y) + 1e-16f;
  float uni = ((w1 * h1 + w2 * h2) - inter) + 1e-16f;
  float iou = inter / uni;
  float sc = pd_s[row_off + (size_t)lab];
  return sqrtf(sc) * powf(iou, 6.0f);
}

__global__ void k_init(unsigned* mn_g, unsigned* mx_g) {
  int b = threadIdx.x;
  if (b < B_N) {
    mn_g[b] = __float_as_uint(1e30f);
    mx_g[b] = 0u;  // bits of +0.0f; am_max >= 0 always, ref value only used when fg exists
  }
}

// One block per (gt n, batch b). Stable top-10 over the amf column, ties ->
// lowest anchor index (jax.lax.top_k semantics). Winners with in_gts && valid
// set fg_mask (mask_pos contribution).
__global__ __launch_bounds__(256) void k_topk(
    const float* __restrict__ pd_s, const float* __restrict__ pd_b,
    const float* __restrict__ anc, const int* __restrict__ gt_l,
    const float* __restrict__ gt_b, const int* __restrict__ mgt,
    int* __restrict__ fg_mask) {
  int n = blockIdx.x, b = blockIdx.y, tid = threadIdx.x;
  if (mgt[b * NGT + n] == 0) return;  // invalid gt: contributes nothing
  int lab = gt_l[b * NGT + n];

  __shared__ float4 gb_s;
  __shared__ unsigned long long warpmax[4];
  __shared__ unsigned long long winners[10];
  if (tid == 0) gb_s = ((const float4*)gt_b)[b * NGT + n];
  __syncthreads();
  float4 gb = gb_s;

  // Per-thread sorted (descending) top-10 of packed keys.
  // key = value_bits<<32 | (0xFFFFFFFF - anchor): max key == max value,
  // tie -> min anchor index. All amf >= +0.0 so uint bit order == float order.
  unsigned long long top[10];
#pragma unroll
  for (int j = 0; j < 10; j++) top[j] = 0ull;

  for (int a = tid; a < A_N; a += 256) {
    float4 pb = ((const float4*)pd_b)[(size_t)b * A_N + a];
    float2 ap = ((const float2*)anc)[a];
    bool ing;
    float v = compute_amf(pd_s, ((size_t)b * A_N + a) * NC, lab, pb, ap, gb, ing);
    unsigned long long key =
        ((unsigned long long)__float_as_uint(v) << 32) |
        (unsigned long long)(0xFFFFFFFFu - (unsigned)a);
#pragma unroll
    for (int j = 0; j < 10; j++) {
      if (key > top[j]) { unsigned long long t = top[j]; top[j] = key; key = t; }
    }
  }

  int lane = tid & 63, wid = tid >> 6;
  for (int r = 0; r < 10; r++) {
    unsigned long long k = top[0];
#pragma unroll
    for (int off = 32; off >= 1; off >>= 1) {
      unsigned long long o = __shfl_xor(k, off, 64);
      k = (o > k) ? o : k;
    }
    if (lane == 0) warpmax[wid] = k;
    __syncthreads();
    unsigned long long g = warpmax[0];
#pragma unroll
    for (int w = 1; w < 4; w++) g = (warpmax[w] > g) ? warpmax[w] : g;
    if (top[0] == g) {  // unique key -> exactly one thread matches
#pragma unroll
      for (int j = 0; j < 9; j++) top[j] = top[j + 1];
      top[9] = 0ull;
    }
    if (tid == 0) winners[r] = g;
    __syncthreads();  // protects warpmax reuse next round + winners visibility
  }

  if (tid < 10) {
    unsigned long long g = winners[tid];
    int a = (int)(0xFFFFFFFFu - (unsigned)(g & 0xFFFFFFFFull));
    float2 ap = ((const float2*)anc)[a];
    float mn = fminf(fminf(ap.x - gb.x, ap.y - gb.y),
                     fminf(gb.z - ap.x, gb.w - ap.y));
    if (mn > 0.0f) atomicOr(&fg_mask[b * A_N + a], 1);
  }
}

// Per-anchor pass: argmax over gts (first-max, jnp.argmax semantics), am_max,
// and per-batch mn/mx reduction over foreground anchors.
__global__ __launch_bounds__(256) void k_row(
    const float* __restrict__ pd_s, const float* __restrict__ pd_b,
    const float* __restrict__ anc, const int* __restrict__ gt_l,
    const float* __restrict__ gt_b, const int* __restrict__ mgt,
    const int* __restrict__ fg_mask, int* __restrict__ gt_idx,
    float* __restrict__ am_max_g, unsigned* __restrict__ mn_g,
    unsigned* __restrict__ mx_g) {
  int b = blockIdx.y;
  int tid = threadIdx.x;
  int a = blockIdx.x * 256 + tid;

  __shared__ float4 gb_s[NGT];
  __shared__ int lab_s[NGT];
  __shared__ int val_s[NGT];
  if (tid < NGT) {
    gb_s[tid] = ((const float4*)gt_b)[b * NGT + tid];
    lab_s[tid] = gt_l[b * NGT + tid];
    val_s[tid] = mgt[b * NGT + tid];
  }
  __syncthreads();

  float am_max = 0.0f;
  bool fg = false;
  if (a < A_N) {
    float4 pb = ((const float4*)pd_b)[(size_t)b * A_N + a];
    float2 ap = ((const float2*)anc)[a];
    size_t row = ((size_t)b * A_N + a) * NC;
    float best = -3.0e38f;
    int bi = 0;
    for (int n = 0; n < NGT; n++) {
      float v;
      if (val_s[n]) {
        bool ing;
        v = compute_amf(pd_s, row, lab_s[n], pb, ap, gb_s[n], ing);
      } else {
        v = -1.0f;  // amf_arg = where(valid, amf, -1)
      }
      if (v > best) { best = v; bi = n; }  // strict > == first-max argmax
    }
    am_max = fmaxf(best, 0.0f);
    fg = fg_mask[(size_t)b * A_N + a] != 0;
    gt_idx[(size_t)b * A_N + a] = bi;
    am_max_g[(size_t)b * A_N + a] = am_max;
  }

  // per-batch mn/mx over fg anchors (values >= 0 -> uint compare ok)
  unsigned mn_c = __float_as_uint(fg ? am_max : 1e30f);
  unsigned mx_c = __float_as_uint(fg ? am_max : 0.0f);
#pragma unroll
  for (int off = 32; off >= 1; off >>= 1) {
    unsigned o1 = __shfl_xor(mn_c, off, 64);
    mn_c = (o1 < mn_c) ? o1 : mn_c;
    unsigned o2 = __shfl_xor(mx_c, off, 64);
    mx_c = (o2 > mx_c) ? o2 : mx_c;
  }
  __shared__ unsigned smn[4], smx[4];
  int lane = tid & 63, wid = tid >> 6;
  if (lane == 0) { smn[wid] = mn_c; smx[wid] = mx_c; }
  __syncthreads();
  if (tid == 0) {
    unsigned m1 = smn[0], m2 = smx[0];
#pragma unroll
    for (int w = 1; w < 4; w++) {
      m1 = (smn[w] < m1) ? smn[w] : m1;
      m2 = (smx[w] > m2) ? smx[w] : m2;
    }
    atomicMin(&mn_g[b], m1);
    atomicMax(&mx_g[b], m2);
  }
}

// Write t_labels, t_bboxes, fg; stash class + norm for the t_scores kernel.
__global__ __launch_bounds__(256) void k_out1(
    const int* __restrict__ gt_l, const float* __restrict__ gt_b,
    const int* __restrict__ fg_mask, const int* __restrict__ gt_idx,
    const float* __restrict__ am_max_g, const unsigned* __restrict__ mn_g,
    const unsigned* __restrict__ mx_g, int* __restrict__ cls_s,
    float* __restrict__ norm_s, float* __restrict__ out) {
  int b = blockIdx.y;
  int a = blockIdx.x * 256 + threadIdx.x;
  if (a >= A_N) return;
  size_t i = (size_t)b * A_N + a;
  bool fg = fg_mask[i] != 0;
  int bi = gt_idx[i];
  float amx = am_max_g[i];
  float mn = __uint_as_float(mn_g[b]);
  float mx = __uint_as_float(mx_g[b]);
  float norm = (amx - mn) / ((mx - mn) + 1e-9f);
  int lab = gt_l[b * NGT + bi];

  out[i] = fg ? (float)lab : (float)NC;  // t_labels (as float32 buffer)
  float4 bb = fg ? ((const float4*)gt_b)[b * NGT + bi]
                 : make_float4(0.f, 0.f, 0.f, 0.f);
  ((float4*)(out + BA))[i] = bb;          // t_bboxes
  out[(size_t)85 * BA + i] = fg ? 1.0f : 0.0f;  // fg
  cls_s[i] = fg ? lab : -1;
  norm_s[i] = fg ? norm : 0.0f;
}

// t_scores: one thread per (b, a, c), fully coalesced 86MB-dominant write.
__global__ __launch_bounds__(256) void k_scores(
    const int* __restrict__ cls_s, const float* __restrict__ norm_s,
    float* __restrict__ out_sc) {
  size_t idx = (size_t)blockIdx.x * 256 + threadIdx.x;
  if (idx >= (size_t)BA * NC) return;
  size_t ai = idx / NC;
  int c = (int)(idx - ai * NC);
  out_sc[idx] = ((int)c == cls_s[ai]) ? norm_s[ai] : 0.0f;
}

extern "C" void kernel_launch(void* const* d_in, const int* in_sizes, int n_in,
                              void* d_out, int out_size, void* d_ws,
                              size_t ws_size, hipStream_t stream) {
  const float* pd_s = (const float*)d_in[0];   // (B, A, 80)
  const float* pd_b = (const float*)d_in[1];   // (B, A, 4)
  const float* anc  = (const float*)d_in[2];   // (A, 2)
  const int*   gt_l = (const int*)d_in[3];     // (B, 64, 1)
  const float* gt_b = (const float*)d_in[4];   // (B, 64, 4)
  const int*   mgt  = (const int*)d_in[5];     // (B, 64, 1) bool->int

  float* out = (float*)d_out;
  char* ws = (char*)d_ws;
  int*      fg_mask  = (int*)ws;
  int*      gt_idx   = (int*)(ws + (size_t)BA * 4);
  float*    am_max_g = (float*)(ws + (size_t)BA * 8);
  int*      cls_s    = (int*)(ws + (size_t)BA * 12);
  float*    norm_s   = (float*)(ws + (size_t)BA * 16);
  unsigned* mn_g     = (unsigned*)(ws + (size_t)BA * 20);
  unsigned* mx_g     = mn_g + B_N;

  hipMemsetAsync(fg_mask, 0, (size_t)BA * 4, stream);
  k_init<<<1, 64, 0, stream>>>(mn_g, mx_g);
  k_topk<<<dim3(NGT, B_N), 256, 0, stream>>>(pd_s, pd_b, anc, gt_l, gt_b, mgt,
                                             fg_mask);
  dim3 g2((A_N + 255) / 256, B_N);
  k_row<<<g2, 256, 0, stream>>>(pd_s, pd_b, anc, gt_l, gt_b, mgt, fg_mask,
                                gt_idx, am_max_g, mn_g, mx_g);
  k_out1<<<g2, 256, 0, stream>>>(gt_l, gt_b, fg_mask, gt_idx, am_max_g, mn_g,
                                 mx_g, cls_s, norm_s, out);
  int nsc_blocks = (int)(((size_t)BA * NC + 255) / 256);
  k_scores<<<nsc_blocks, 256, 0, stream>>>(cls_s, norm_s, out + (size_t)5 * BA);
}

// Round 2
// 264.264 us; speedup vs baseline: 1.2955x; 1.2955x over previous
//
#include <hip/hip_runtime.h>

#define A_N 8400
#define B_N 32
#define NGT 64
#define NC  80
#define BA  (B_N * A_N)
#define ACH 33  // ceil(8400/256) anchor chunks

// Compute the task-aligned metric amf = (score^0.5 * iou^6) * in_gts for one
// (anchor, gt) pair, matching the numpy/JAX reference op-for-op.
// fp contract off so mul+add are not fused into fma (round-1 verified: bit-exact
// vs numpy, absmax 0.0 -- do not change the op order or powf here).
__device__ __forceinline__ float compute_amf(const float* __restrict__ pd_s,
                                             size_t row_off, int lab,
                                             float4 pb, float2 ap, float4 gb,
                                             bool& ing) {
#pragma clang fp contract(off)
  float lt0 = ap.x - gb.x;
  float lt1 = ap.y - gb.y;
  float rb0 = gb.z - ap.x;
  float rb1 = gb.w - ap.y;
  float mn = fminf(fminf(lt0, lt1), fminf(rb0, rb1));
  ing = mn > 0.0f;
  if (!ing) return 0.0f;   // align * False == +0.0 exactly
  float iw = fminf(gb.z, pb.z) - fmaxf(gb.x, pb.x);
  iw = fmaxf(iw, 0.0f);
  float ih = fminf(gb.w, pb.w) - fmaxf(gb.y, pb.y);
  ih = fmaxf(ih, 0.0f);
  float inter = iw * ih;
  float w1 = gb.z - gb.x, h1 = (gb.w - gb.y) + 1e-16f;
  float w2 = pb.z - pb.x, h2 = (pb.w - pb.y) + 1e-16f;
  float uni = ((w1 * h1 + w2 * h2) - inter) + 1e-16f;
  float iou = inter / uni;
  float sc = pd_s[row_off + (size_t)lab];
  return sqrtf(sc) * powf(iou, 6.0f);
}

__global__ void k_init(unsigned* mn_g, unsigned* mx_g) {
  int b = threadIdx.x;
  if (b < B_N) {
    mn_g[b] = __float_as_uint(1e30f);
    mx_g[b] = 0u;  // +0.0f bits; am_max >= 0 always
  }
}

// ---------------------------------------------------------------------------
// FAST PATH: materialize M[b][n][a] once, then stream it.
// ---------------------------------------------------------------------------

// Producer: one thread per (anchor, gt, batch). 67k blocks -> perfect balance,
// latency hidden by sheer parallelism. Bit-identical amf to round 1.
__global__ __launch_bounds__(256) void k_amf(
    const float* __restrict__ pd_s, const float* __restrict__ pd_b,
    const float* __restrict__ anc, const int* __restrict__ gt_l,
    const float* __restrict__ gt_b, const int* __restrict__ mgt,
    float* __restrict__ M) {
  int b = blockIdx.y, n = blockIdx.z;
  if (mgt[b * NGT + n] == 0) return;  // invalid gt: column never read
  int a = blockIdx.x * 256 + threadIdx.x;
  if (a >= A_N) return;
  float4 gb = ((const float4*)gt_b)[b * NGT + n];
  int lab = gt_l[b * NGT + n];
  float4 pb = ((const float4*)pd_b)[(size_t)b * A_N + a];
  float2 ap = ((const float2*)anc)[a];
  bool ing;
  float v = compute_amf(pd_s, ((size_t)b * A_N + a) * NC, lab, pb, ap, gb, ing);
  M[((size_t)(b * NGT + n)) * A_N + a] = v;
}

// Stable top-10 per (b, gt) column of M; ties -> lowest anchor index
// (jax.lax.top_k semantics). Grid is b-fastest for CU load balance.
__global__ __launch_bounds__(256) void k_topk2(
    const float* __restrict__ M, const float* __restrict__ anc,
    const float* __restrict__ gt_b, const int* __restrict__ mgt,
    int* __restrict__ fg_mask) {
  int b = blockIdx.x, n = blockIdx.y, tid = threadIdx.x;
  if (mgt[b * NGT + n] == 0) return;
  float4 gb = ((const float4*)gt_b)[b * NGT + n];
  const float* col = M + ((size_t)(b * NGT + n)) * A_N;

  // key = value_bits<<32 | (0xFFFFFFFF - anchor): max key == max value,
  // tie -> min anchor index. All amf >= +0.0 so uint bit order == float order.
  unsigned long long top[10];
#pragma unroll
  for (int j = 0; j < 10; j++) top[j] = 0ull;

  for (int a = tid; a < A_N; a += 256) {
    float v = col[a];
    unsigned long long key =
        ((unsigned long long)__float_as_uint(v) << 32) |
        (unsigned long long)(0xFFFFFFFFu - (unsigned)a);
#pragma unroll
    for (int j = 0; j < 10; j++) {
      if (key > top[j]) { unsigned long long t = top[j]; top[j] = key; key = t; }
    }
  }

  __shared__ unsigned long long warpmax[4];
  __shared__ unsigned long long winners[10];
  int lane = tid & 63, wid = tid >> 6;
  for (int r = 0; r < 10; r++) {
    unsigned long long k = top[0];
#pragma unroll
    for (int off = 32; off >= 1; off >>= 1) {
      unsigned long long o = __shfl_xor(k, off, 64);
      k = (o > k) ? o : k;
    }
    if (lane == 0) warpmax[wid] = k;
    __syncthreads();
    unsigned long long g = warpmax[0];
#pragma unroll
    for (int w = 1; w < 4; w++) g = (warpmax[w] > g) ? warpmax[w] : g;
    if (top[0] == g) {  // unique key -> exactly one thread matches
#pragma unroll
      for (int j = 0; j < 9; j++) top[j] = top[j + 1];
      top[9] = 0ull;
    }
    if (tid == 0) winners[r] = g;
    __syncthreads();
  }

  if (tid < 10) {
    unsigned long long g = winners[tid];
    int a = (int)(0xFFFFFFFFu - (unsigned)(g & 0xFFFFFFFFull));
    float2 ap = ((const float2*)anc)[a];
    float mn = fminf(fminf(ap.x - gb.x, ap.y - gb.y),
                     fminf(gb.z - ap.x, gb.w - ap.y));
    if (mn > 0.0f) atomicOr(&fg_mask[b * A_N + a], 1);
  }
}

// Per-anchor argmax over gts (first-max == jnp.argmax) streaming M rows,
// plus the per-batch mn/mx reduction over foreground anchors.
// mask_gt is a prefix mask (arange < count), so valid n == [0, cnt).
// Invalid entries are -1 in the reference and amf >= 0, so they never win.
__global__ __launch_bounds__(256) void k_row2(
    const float* __restrict__ M, const int* __restrict__ mgt,
    const int* __restrict__ fg_mask, int* __restrict__ gt_idx,
    float* __restrict__ am_max_g, unsigned* __restrict__ mn_g,
    unsigned* __restrict__ mx_g) {
  int b = blockIdx.y;
  int tid = threadIdx.x;
  int a = blockIdx.x * 256 + tid;

  __shared__ int cnt_s;
  if (tid < 64) {
    int v = mgt[b * NGT + tid];
    unsigned long long m = __ballot(v != 0);
    if (tid == 0) cnt_s = __popcll(m);
  }
  __syncthreads();
  int cnt = cnt_s;

  float am_max = 0.0f;
  bool fg = false;
  if (a < A_N) {
    const float* Mb = M + ((size_t)b * NGT) * A_N + a;
    float best = -3.0e38f;
    int bi = 0;
#pragma unroll 4
    for (int n = 0; n < cnt; n++) {
      float v = Mb[(size_t)n * A_N];
      if (v > best) { best = v; bi = n; }  // strict > == first-max argmax
    }
    am_max = fmaxf(best, 0.0f);
    fg = fg_mask[(size_t)b * A_N + a] != 0;
    gt_idx[(size_t)b * A_N + a] = bi;
    am_max_g[(size_t)b * A_N + a] = am_max;
  }

  unsigned mn_c = __float_as_uint(fg ? am_max : 1e30f);
  unsigned mx_c = __float_as_uint(fg ? am_max : 0.0f);
#pragma unroll
  for (int off = 32; off >= 1; off >>= 1) {
    unsigned o1 = __shfl_xor(mn_c, off, 64);
    mn_c = (o1 < mn_c) ? o1 : mn_c;
    unsigned o2 = __shfl_xor(mx_c, off, 64);
    mx_c = (o2 > mx_c) ? o2 : mx_c;
  }
  __shared__ unsigned smn[4], smx[4];
  int lane = tid & 63, wid = tid >> 6;
  if (lane == 0) { smn[wid] = mn_c; smx[wid] = mx_c; }
  __syncthreads();
  if (tid == 0) {
    unsigned m1 = smn[0], m2 = smx[0];
#pragma unroll
    for (int w = 1; w < 4; w++) {
      m1 = (smn[w] < m1) ? smn[w] : m1;
      m2 = (smx[w] > m2) ? smx[w] : m2;
    }
    atomicMin(&mn_g[b], m1);
    atomicMax(&mx_g[b], m2);
  }
}

// ---------------------------------------------------------------------------
// FALLBACK PATH (ws too small for M): round-1 kernels, verified correct.
// ---------------------------------------------------------------------------

__global__ __launch_bounds__(256) void k_topk_fb(
    const float* __restrict__ pd_s, const float* __restrict__ pd_b,
    const float* __restrict__ anc, const int* __restrict__ gt_l,
    const float* __restrict__ gt_b, const int* __restrict__ mgt,
    int* __restrict__ fg_mask) {
  int b = blockIdx.x, n = blockIdx.y, tid = threadIdx.x;
  if (mgt[b * NGT + n] == 0) return;
  int lab = gt_l[b * NGT + n];
  float4 gb = ((const float4*)gt_b)[b * NGT + n];

  unsigned long long top[10];
#pragma unroll
  for (int j = 0; j < 10; j++) top[j] = 0ull;

  for (int a = tid; a < A_N; a += 256) {
    float4 pb = ((const float4*)pd_b)[(size_t)b * A_N + a];
    float2 ap = ((const float2*)anc)[a];
    bool ing;
    float v = compute_amf(pd_s, ((size_t)b * A_N + a) * NC, lab, pb, ap, gb, ing);
    unsigned long long key =
        ((unsigned long long)__float_as_uint(v) << 32) |
        (unsigned long long)(0xFFFFFFFFu - (unsigned)a);
#pragma unroll
    for (int j = 0; j < 10; j++) {
      if (key > top[j]) { unsigned long long t = top[j]; top[j] = key; key = t; }
    }
  }

  __shared__ unsigned long long warpmax[4];
  __shared__ unsigned long long winners[10];
  int lane = tid & 63, wid = tid >> 6;
  for (int r = 0; r < 10; r++) {
    unsigned long long k = top[0];
#pragma unroll
    for (int off = 32; off >= 1; off >>= 1) {
      unsigned long long o = __shfl_xor(k, off, 64);
      k = (o > k) ? o : k;
    }
    if (lane == 0) warpmax[wid] = k;
    __syncthreads();
    unsigned long long g = warpmax[0];
#pragma unroll
    for (int w = 1; w < 4; w++) g = (warpmax[w] > g) ? warpmax[w] : g;
    if (top[0] == g) {
#pragma unroll
      for (int j = 0; j < 9; j++) top[j] = top[j + 1];
      top[9] = 0ull;
    }
    if (tid == 0) winners[r] = g;
    __syncthreads();
  }

  if (tid < 10) {
    unsigned long long g = winners[tid];
    int a = (int)(0xFFFFFFFFu - (unsigned)(g & 0xFFFFFFFFull));
    float2 ap = ((const float2*)anc)[a];
    float mn = fminf(fminf(ap.x - gb.x, ap.y - gb.y),
                     fminf(gb.z - ap.x, gb.w - ap.y));
    if (mn > 0.0f) atomicOr(&fg_mask[b * A_N + a], 1);
  }
}

__global__ __launch_bounds__(256) void k_row_fb(
    const float* __restrict__ pd_s, const float* __restrict__ pd_b,
    const float* __restrict__ anc, const int* __restrict__ gt_l,
    const float* __restrict__ gt_b, const int* __restrict__ mgt,
    const int* __restrict__ fg_mask, int* __restrict__ gt_idx,
    float* __restrict__ am_max_g, unsigned* __restrict__ mn_g,
    unsigned* __restrict__ mx_g) {
  int b = blockIdx.y;
  int tid = threadIdx.x;
  int a = blockIdx.x * 256 + tid;

  __shared__ float4 gb_s[NGT];
  __shared__ int lab_s[NGT];
  __shared__ int val_s[NGT];
  if (tid < NGT) {
    gb_s[tid] = ((const float4*)gt_b)[b * NGT + tid];
    lab_s[tid] = gt_l[b * NGT + tid];
    val_s[tid] = mgt[b * NGT + tid];
  }
  __syncthreads();

  float am_max = 0.0f;
  bool fg = false;
  if (a < A_N) {
    float4 pb = ((const float4*)pd_b)[(size_t)b * A_N + a];
    float2 ap = ((const float2*)anc)[a];
    size_t row = ((size_t)b * A_N + a) * NC;
    float best = -3.0e38f;
    int bi = 0;
    for (int n = 0; n < NGT; n++) {
      float v;
      if (val_s[n]) {
        bool ing;
        v = compute_amf(pd_s, row, lab_s[n], pb, ap, gb_s[n], ing);
      } else {
        v = -1.0f;
      }
      if (v > best) { best = v; bi = n; }
    }
    am_max = fmaxf(best, 0.0f);
    fg = fg_mask[(size_t)b * A_N + a] != 0;
    gt_idx[(size_t)b * A_N + a] = bi;
    am_max_g[(size_t)b * A_N + a] = am_max;
  }

  unsigned mn_c = __float_as_uint(fg ? am_max : 1e30f);
  unsigned mx_c = __float_as_uint(fg ? am_max : 0.0f);
#pragma unroll
  for (int off = 32; off >= 1; off >>= 1) {
    unsigned o1 = __shfl_xor(mn_c, off, 64);
    mn_c = (o1 < mn_c) ? o1 : mn_c;
    unsigned o2 = __shfl_xor(mx_c, off, 64);
    mx_c = (o2 > mx_c) ? o2 : mx_c;
  }
  __shared__ unsigned smn[4], smx[4];
  int lane = tid & 63, wid = tid >> 6;
  if (lane == 0) { smn[wid] = mn_c; smx[wid] = mx_c; }
  __syncthreads();
  if (tid == 0) {
    unsigned m1 = smn[0], m2 = smx[0];
#pragma unroll
    for (int w = 1; w < 4; w++) {
      m1 = (smn[w] < m1) ? smn[w] : m1;
      m2 = (smx[w] > m2) ? smx[w] : m2;
    }
    atomicMin(&mn_g[b], m1);
    atomicMax(&mx_g[b], m2);
  }
}

// ---------------------------------------------------------------------------
// Output writers
// ---------------------------------------------------------------------------

__global__ __launch_bounds__(256) void k_out1(
    const int* __restrict__ gt_l, const float* __restrict__ gt_b,
    const int* __restrict__ fg_mask, const int* __restrict__ gt_idx,
    const float* __restrict__ am_max_g, const unsigned* __restrict__ mn_g,
    const unsigned* __restrict__ mx_g, int* __restrict__ cls_s,
    float* __restrict__ norm_s, float* __restrict__ out) {
  int b = blockIdx.y;
  int a = blockIdx.x * 256 + threadIdx.x;
  if (a >= A_N) return;
  size_t i = (size_t)b * A_N + a;
  bool fg = fg_mask[i] != 0;
  int bi = gt_idx[i];
  float amx = am_max_g[i];
  float mn = __uint_as_float(mn_g[b]);
  float mx = __uint_as_float(mx_g[b]);
  float norm = (amx - mn) / ((mx - mn) + 1e-9f);
  int lab = gt_l[b * NGT + bi];

  out[i] = fg ? (float)lab : (float)NC;  // t_labels
  float4 bb = fg ? ((const float4*)gt_b)[b * NGT + bi]
                 : make_float4(0.f, 0.f, 0.f, 0.f);
  ((float4*)(out + BA))[i] = bb;          // t_bboxes
  out[(size_t)85 * BA + i] = fg ? 1.0f : 0.0f;  // fg
  cls_s[i] = fg ? lab : -1;
  norm_s[i] = fg ? norm : 0.0f;
}

// t_scores: one thread per 4 classes of one anchor, float4 stores (86 MB).
__global__ __launch_bounds__(256) void k_scores4(
    const int* __restrict__ cls_s, const float* __restrict__ norm_s,
    float4* __restrict__ out_sc) {
  size_t t = (size_t)blockIdx.x * 256 + threadIdx.x;
  if (t >= (size_t)BA * (NC / 4)) return;
  size_t ai = t / (NC / 4);
  int c0 = (int)(t - ai * (NC / 4)) * 4;
  int cls = cls_s[ai];
  float nv = norm_s[ai];
  float4 r;
  r.x = (c0 == cls) ? nv : 0.0f;
  r.y = (c0 + 1 == cls) ? nv : 0.0f;
  r.z = (c0 + 2 == cls) ? nv : 0.0f;
  r.w = (c0 + 3 == cls) ? nv : 0.0f;
  out_sc[t] = r;
}

extern "C" void kernel_launch(void* const* d_in, const int* in_sizes, int n_in,
                              void* d_out, int out_size, void* d_ws,
                              size_t ws_size, hipStream_t stream) {
  const float* pd_s = (const float*)d_in[0];   // (B, A, 80)
  const float* pd_b = (const float*)d_in[1];   // (B, A, 4)
  const float* anc  = (const float*)d_in[2];   // (A, 2)
  const int*   gt_l = (const int*)d_in[3];     // (B, 64, 1)
  const float* gt_b = (const float*)d_in[4];   // (B, 64, 4)
  const int*   mgt  = (const int*)d_in[5];     // (B, 64, 1)

  float* out = (float*)d_out;
  char* ws = (char*)d_ws;

  const size_t M_BYTES = (size_t)B_N * NGT * A_N * 4;  // 68.8 MB
  const size_t SMALL = (size_t)BA * 4;
  bool fast = ws_size >= M_BYTES + 5 * SMALL + 256;

  float* M = (float*)ws;
  char* small_base = fast ? (ws + M_BYTES) : ws;
  int*      fg_mask  = (int*)small_base;
  int*      gt_idx   = (int*)(small_base + SMALL);
  float*    am_max_g = (float*)(small_base + 2 * SMALL);
  int*      cls_s    = (int*)(small_base + 3 * SMALL);
  float*    norm_s   = (float*)(small_base + 4 * SMALL);
  unsigned* mn_g     = (unsigned*)(small_base + 5 * SMALL);
  unsigned* mx_g     = mn_g + B_N;

  hipMemsetAsync(fg_mask, 0, SMALL, stream);
  k_init<<<1, 64, 0, stream>>>(mn_g, mx_g);

  dim3 g2((A_N + 255) / 256, B_N);
  if (fast) {
    k_amf<<<dim3(ACH, B_N, NGT), 256, 0, stream>>>(pd_s, pd_b, anc, gt_l, gt_b,
                                                   mgt, M);
    k_topk2<<<dim3(B_N, NGT), 256, 0, stream>>>(M, anc, gt_b, mgt, fg_mask);
    k_row2<<<g2, 256, 0, stream>>>(M, mgt, fg_mask, gt_idx, am_max_g, mn_g,
                                   mx_g);
  } else {
    k_topk_fb<<<dim3(B_N, NGT), 256, 0, stream>>>(pd_s, pd_b, anc, gt_l, gt_b,
                                                  mgt, fg_mask);
    k_row_fb<<<g2, 256, 0, stream>>>(pd_s, pd_b, anc, gt_l, gt_b, mgt, fg_mask,
                                     gt_idx, am_max_g, mn_g, mx_g);
  }
  k_out1<<<g2, 256, 0, stream>>>(gt_l, gt_b, fg_mask, gt_idx, am_max_g, mn_g,
                                 mx_g, cls_s, norm_s, out);
  int nsc_blocks = (int)(((size_t)BA * (NC / 4) + 255) / 256);
  k_scores4<<<nsc_blocks, 256, 0, stream>>>(cls_s, norm_s,
                                            (float4*)(out + (size_t)5 * BA));
}